// Round 1
// 4428.353 us; speedup vs baseline: 1.0036x; 1.0036x over previous
//
#include <hip/hip_runtime.h>

#define Bn 64
#define Tn 2048
#define In 128
#define Hn 256
#define RS 512  // row stride in f16 elements for pre/out rows (1024 B)

typedef _Float16 h2 __attribute__((ext_vector_type(2)));
typedef _Float16 f16x8 __attribute__((ext_vector_type(8)));
typedef float f32x4 __attribute__((ext_vector_type(4)));

__device__ __forceinline__ float fast_sigmoid(float x) {
    return 1.0f / (1.0f + __expf(-x));
}
__device__ __forceinline__ float fast_tanh(float x) {
    return 2.0f / (1.0f + __expf(-2.0f * x)) - 1.0f;
}
__device__ __forceinline__ h2 bc2(float f) {
    return __builtin_bit_cast(h2, f);
}

// ---------------------------------------------------------------------------
// K1: pre0[m][512] (f16, in d_out) = X[m][0:128] @ [Wih0 | Wax0] + [bh0 | ba0]
// ---------------------------------------------------------------------------
__global__ void gemm_x_kernel(const float* __restrict__ X,
                              const float* __restrict__ Wih0, const float* __restrict__ bh0,
                              const float* __restrict__ Wax0, const float* __restrict__ ba0,
                              _Float16* __restrict__ pre)
{
    __shared__ __align__(16) float Xs[64 * In];  // 32 KB
    const int m0 = blockIdx.x * 64;
    const int s  = blockIdx.y;
    const float* __restrict__ W    = s ? Wax0 : Wih0;
    const float* __restrict__ bias = s ? ba0  : bh0;

    {
        const float4* __restrict__ src = reinterpret_cast<const float4*>(X + (size_t)m0 * In);
        float4* __restrict__ dst = reinterpret_cast<float4*>(Xs);
        #pragma unroll
        for (int i = 0; i < 8; ++i) dst[threadIdx.x + 256 * i] = src[threadIdx.x + 256 * i];
    }
    __syncthreads();

    const int c  = threadIdx.x & 63;
    const int rg = threadIdx.x >> 6;
    const int mr = rg * 16;

    float acc[16][4];
    #pragma unroll
    for (int u = 0; u < 4; ++u) {
        const float bv = bias[c + 64 * u];
        #pragma unroll
        for (int r = 0; r < 16; ++r) acc[r][u] = bv;
    }

    const float4* __restrict__ Xs4 = reinterpret_cast<const float4*>(Xs);
    #pragma unroll 4
    for (int kc = 0; kc < 32; ++kc) {
        float wv[4][4];
        #pragma unroll
        for (int kk = 0; kk < 4; ++kk)
            #pragma unroll
            for (int u = 0; u < 4; ++u)
                wv[kk][u] = W[(size_t)(4 * kc + kk) * Hn + c + 64 * u];
        #pragma unroll
        for (int r = 0; r < 16; ++r) {
            const float4 xv = Xs4[(mr + r) * 32 + kc];
            #pragma unroll
            for (int u = 0; u < 4; ++u)
                acc[r][u] += xv.x * wv[0][u] + xv.y * wv[1][u] + xv.z * wv[2][u] + xv.w * wv[3][u];
        }
    }

    #pragma unroll
    for (int r = 0; r < 16; ++r)
        #pragma unroll
        for (int u = 0; u < 4; ++u)
            pre[(size_t)(m0 + mr + r) * RS + s * Hn + c + 64 * u] = (_Float16)acc[r][u];
}

// ---------------------------------------------------------------------------
// K3: pre1 (in-place over pre rows) = h0seq(f16) @ [Wih1 | Wax1] + bias
// ---------------------------------------------------------------------------
__global__ void gemm_h_kernel(_Float16* __restrict__ pre,
                              const float* __restrict__ Wih1, const float* __restrict__ bh1,
                              const float* __restrict__ Wax1, const float* __restrict__ ba1)
{
    __shared__ __align__(16) _Float16 Hs[32 * Hn];  // 16 KB
    const int m0 = blockIdx.x * 32;

    {
        float4* __restrict__ dst = reinterpret_cast<float4*>(Hs);
        #pragma unroll
        for (int q = 0; q < 4; ++q) {
            const int id  = threadIdx.x + 256 * q;
            const int row = id >> 5;
            const int off = id & 31;
            const float4* __restrict__ src =
                reinterpret_cast<const float4*>(pre + (size_t)(m0 + row) * RS);
            dst[row * 32 + off] = src[off];
        }
    }
    __syncthreads();

    const int c  = threadIdx.x & 63;
    const int rg = threadIdx.x >> 6;
    const int mr = rg * 8;

    const float* Wp[8];
    float acc[8][8];
    #pragma unroll
    for (int u = 0; u < 8; ++u) {
        const int colu = c + 64 * u;
        const float bv = (colu < Hn) ? bh1[colu] : ba1[colu - Hn];
        Wp[u] = (colu < Hn) ? (Wih1 + colu) : (Wax1 + (colu - Hn));
        #pragma unroll
        for (int r = 0; r < 8; ++r) acc[r][u] = bv;
    }

    const float2* __restrict__ Hs2 = reinterpret_cast<const float2*>(Hs);
    #pragma unroll 2
    for (int kc = 0; kc < 64; ++kc) {
        float wv[4][8];
        #pragma unroll
        for (int kk = 0; kk < 4; ++kk)
            #pragma unroll
            for (int u = 0; u < 8; ++u)
                wv[kk][u] = Wp[u][(size_t)(4 * kc + kk) * Hn];
        #pragma unroll
        for (int r = 0; r < 8; ++r) {
            const float2 q = Hs2[(mr + r) * 64 + kc];
            const h2 p0 = bc2(q.x), p1 = bc2(q.y);
            const float f0 = (float)p0.x, f1 = (float)p0.y, f2 = (float)p1.x, f3 = (float)p1.y;
            #pragma unroll
            for (int u = 0; u < 8; ++u)
                acc[r][u] += f0 * wv[0][u] + f1 * wv[1][u] + f2 * wv[2][u] + f3 * wv[3][u];
        }
    }

    #pragma unroll
    for (int r = 0; r < 8; ++r)
        #pragma unroll
        for (int u = 0; u < 8; ++u)
            pre[(size_t)(m0 + mr + r) * RS + c + 64 * u] = (_Float16)acc[r][u];
}

// ---------------------------------------------------------------------------
// MFMA scan. 64 blocks x 512 threads (8 waves). Wave w: matvec mv=w>>2
// (0=U,1=A), col-quarter nq=w&3. Weights resident in VGPRs.
//
// This revision amortizes the per-step vmcnt(0) drain at __syncthreads:
//  - global pre-row prefetch batched 8 rows/chunk into regs, spilled to a
//    column-private LDS buffer (pbuf) at chunk end;
//  - global h/out stores batched 8 rows/chunk, sourced from an 8-slot LDS
//    h ring (hring) / f32 out ring (oring).
// All chunk-flush LDS traffic is column-private (writer thread == reader
// thread), so no extra barrier is needed; the per-step barriers provide all
// cross-thread ordering. In-place row aliasing stays safe: reads of row t
// are drained >= 1 chunk before any write to row t.
// ---------------------------------------------------------------------------
__global__ __launch_bounds__(512, 2)
void scan_mfma_kernel(_Float16* __restrict__ pre,
                      const float* __restrict__ WU, const float* __restrict__ WA,
                      float* __restrict__ outf, float* __restrict__ hfin, int writeF32)
{
    __shared__ __align__(16) _Float16 hring[8][Hn];    // 4 KB, h history ring
    __shared__ __align__(8)  float    yua[Hn][2];      // 2 KB
    __shared__ __align__(16) float    pbuf[8][Hn][2];  // 16 KB, prefetched (pU,pA)
    __shared__ __align__(16) float    oring[8][Hn];    // 8 KB, f32 out history (layer 1)

    const int b    = blockIdx.x;
    const int tid  = threadIdx.x;
    const int lane = tid & 63;
    const int wv   = tid >> 6;       // wave id (uniform)
    const int mv   = wv >> 2;        // 0 = U (tanh), 1 = A (sigmoid)
    const int nq   = wv & 3;         // 64-col quarter
    const int g    = lane >> 4;      // k-subgroup within wave
    const int cl   = lane & 15;      // col within 16-tile

    // ---- B fragments (weights) resident in VGPRs: bfrag[kc][nt] ----
    const float* __restrict__ W = mv ? WA : WU;
    f16x8 bfrag[8][4];
    #pragma unroll
    for (int kc = 0; kc < 8; ++kc) {
        #pragma unroll
        for (int nt = 0; nt < 4; ++nt) {
            const int n  = 64 * nq + 16 * nt + cl;
            const int k0 = 32 * kc + 8 * g;
            f16x8 f;
            #pragma unroll
            for (int jj = 0; jj < 8; ++jj)
                f[jj] = (_Float16)W[(size_t)(k0 + jj) * Hn + n];
            bfrag[kc][nt] = f;
        }
    }

    _Float16* __restrict__ rowbase = pre + (size_t)b * Tn * RS;
    const int j = tid;               // activation column for tid < 256
    float hprev = 0.0f;

    // prologue: h0 = 0, prefetch rows 0..7 into pbuf
    if (tid < Hn) {
        hring[0][tid] = (_Float16)0.0f;
        #pragma unroll
        for (int k = 0; k < 8; ++k) {
            pbuf[k][j][0] = (float)rowbase[(size_t)k * RS + j];
            pbuf[k][j][1] = (float)rowbase[(size_t)k * RS + Hn + j];
        }
    }
    __syncthreads();

    for (int t0 = 0; t0 < Tn; t0 += 8) {
        // ---- issue batched prefetch of rows t0+8 .. t0+15 (regs; consumed
        //      at chunk end). Drained once per chunk by the first barrier. ----
        float pUn[8], pAn[8];
        if (tid < Hn) {
            #pragma unroll
            for (int k = 0; k < 8; ++k) {
                int tn = t0 + 8 + k;
                if (tn > Tn - 1) tn = Tn - 1;
                pUn[k] = (float)rowbase[(size_t)tn * RS + j];
                pAn[k] = (float)rowbase[(size_t)tn * RS + Hn + j];
            }
        }

        #pragma unroll 1
        for (int ph = 0; ph < 8; ++ph) {
            const int t = t0 + ph;

            // ---- A fragments from current h ring slot ----
            const float4* __restrict__ hb =
                reinterpret_cast<const float4*>(&hring[t & 7][0]);
            f16x8 af[8];
            #pragma unroll
            for (int kc = 0; kc < 8; ++kc)
                af[kc] = __builtin_bit_cast(f16x8, hb[kc * 4 + g]);

            // ---- MFMA K-loop: 4 N-tiles x 8 K-chunks ----
            const f32x4 z = {0.0f, 0.0f, 0.0f, 0.0f};
            f32x4 a0 = __builtin_amdgcn_mfma_f32_16x16x32_f16(af[0], bfrag[0][0], z, 0, 0, 0);
            f32x4 a1 = __builtin_amdgcn_mfma_f32_16x16x32_f16(af[0], bfrag[0][1], z, 0, 0, 0);
            f32x4 a2 = __builtin_amdgcn_mfma_f32_16x16x32_f16(af[0], bfrag[0][2], z, 0, 0, 0);
            f32x4 a3 = __builtin_amdgcn_mfma_f32_16x16x32_f16(af[0], bfrag[0][3], z, 0, 0, 0);
            #pragma unroll
            for (int kc = 1; kc < 8; ++kc) {
                a0 = __builtin_amdgcn_mfma_f32_16x16x32_f16(af[kc], bfrag[kc][0], a0, 0, 0, 0);
                a1 = __builtin_amdgcn_mfma_f32_16x16x32_f16(af[kc], bfrag[kc][1], a1, 0, 0, 0);
                a2 = __builtin_amdgcn_mfma_f32_16x16x32_f16(af[kc], bfrag[kc][2], a2, 0, 0, 0);
                a3 = __builtin_amdgcn_mfma_f32_16x16x32_f16(af[kc], bfrag[kc][3], a3, 0, 0, 0);
            }

            // ---- publish y (rows identical -> any component) ----
            const float yv = (g == 0) ? a0.x : (g == 1) ? a1.x : (g == 2) ? a2.x : a3.x;
            yua[64 * nq + lane][mv] = yv;
            __syncthreads();   // y ready; h reads of this step done

            if (tid < Hn) {
                const float yU = yua[j][0] + pbuf[ph][j][0];
                const float yA = yua[j][1] + pbuf[ph][j][1];
                const float cand  = fast_tanh(yU);
                const float alpha = fast_sigmoid(yA);
                const float hn = alpha * cand + (1.0f - alpha) * hprev;
                hprev = hn;
                hring[(t + 1) & 7][j] = (_Float16)hn;
                if (writeF32) oring[ph][j] = hn;   // keep f32 output exact
            }
            __syncthreads();   // hring[(t+1)&7] ready for next step
        }

        // ---- chunk flush (column-private LDS; no barrier needed) ----
        if (tid < Hn) {
            #pragma unroll
            for (int k = 0; k < 8; ++k) {
                pbuf[k][j][0] = pUn[k];
                pbuf[k][j][1] = pAn[k];
            }
            if (writeF32) {
                #pragma unroll
                for (int k = 0; k < 8; ++k)
                    outf[((size_t)b * Tn + (t0 + k)) * Hn + j] = oring[k][j];
            } else {
                #pragma unroll
                for (int k = 0; k < 8; ++k)
                    rowbase[(size_t)(t0 + k) * RS + j] = hring[(k + 1) & 7][j];
            }
        }
    }

    if (tid < Hn) hfin[b * Hn + j] = hprev;
}

extern "C" void kernel_launch(void* const* d_in, const int* in_sizes, int n_in,
                              void* d_out, int out_size, void* d_ws, size_t ws_size,
                              hipStream_t stream) {
    const float* X    = (const float*)d_in[0];
    const float* Wih0 = (const float*)d_in[1];
    const float* Whh0 = (const float*)d_in[2];
    const float* bh0  = (const float*)d_in[3];
    const float* Wax0 = (const float*)d_in[4];
    const float* Wah0 = (const float*)d_in[5];
    const float* ba0  = (const float*)d_in[6];
    const float* Wih1 = (const float*)d_in[7];
    const float* Whh1 = (const float*)d_in[8];
    const float* bh1  = (const float*)d_in[9];
    const float* Wax1 = (const float*)d_in[10];
    const float* Wah1 = (const float*)d_in[11];
    const float* ba1  = (const float*)d_in[12];

    float* outf = (float*)d_out;
    float* hfin = outf + (size_t)Bn * Tn * Hn;
    _Float16* pre = (_Float16*)d_out;

    gemm_x_kernel<<<dim3((Bn * Tn) / 64, 2), 256, 0, stream>>>(X, Wih0, bh0, Wax0, ba0, pre);
    scan_mfma_kernel<<<dim3(Bn), 512, 0, stream>>>(pre, Whh0, Wah0, outf, hfin, 0);
    gemm_h_kernel<<<dim3((Bn * Tn) / 32), 256, 0, stream>>>(pre, Wih1, bh1, Wax1, ba1);
    scan_mfma_kernel<<<dim3(Bn), 512, 0, stream>>>(pre, Whh1, Wah1, outf, hfin + Bn * Hn, 1);
}

// Round 2
// 4268.990 us; speedup vs baseline: 1.0411x; 1.0373x over previous
//
#include <hip/hip_runtime.h>

#define Bn 64
#define Tn 2048
#define In 128
#define Hn 256
#define RS 512  // row stride in f16 elements for pre/out rows (1024 B)

typedef _Float16 h2 __attribute__((ext_vector_type(2)));
typedef _Float16 f16x8 __attribute__((ext_vector_type(8)));
typedef float f32x4 __attribute__((ext_vector_type(4)));

__device__ __forceinline__ float fast_sigmoid(float x) {
    return 1.0f / (1.0f + __expf(-x));
}
__device__ __forceinline__ float fast_tanh(float x) {
    return 2.0f / (1.0f + __expf(-2.0f * x)) - 1.0f;
}
__device__ __forceinline__ h2 bc2(float f) {
    return __builtin_bit_cast(h2, f);
}

// ---------------------------------------------------------------------------
// K1: pre0[m][512] (f16, in d_out) = X[m][0:128] @ [Wih0 | Wax0] + [bh0 | ba0]
// ---------------------------------------------------------------------------
__global__ void gemm_x_kernel(const float* __restrict__ X,
                              const float* __restrict__ Wih0, const float* __restrict__ bh0,
                              const float* __restrict__ Wax0, const float* __restrict__ ba0,
                              _Float16* __restrict__ pre)
{
    __shared__ __align__(16) float Xs[64 * In];  // 32 KB
    const int m0 = blockIdx.x * 64;
    const int s  = blockIdx.y;
    const float* __restrict__ W    = s ? Wax0 : Wih0;
    const float* __restrict__ bias = s ? ba0  : bh0;

    {
        const float4* __restrict__ src = reinterpret_cast<const float4*>(X + (size_t)m0 * In);
        float4* __restrict__ dst = reinterpret_cast<float4*>(Xs);
        #pragma unroll
        for (int i = 0; i < 8; ++i) dst[threadIdx.x + 256 * i] = src[threadIdx.x + 256 * i];
    }
    __syncthreads();

    const int c  = threadIdx.x & 63;
    const int rg = threadIdx.x >> 6;
    const int mr = rg * 16;

    float acc[16][4];
    #pragma unroll
    for (int u = 0; u < 4; ++u) {
        const float bv = bias[c + 64 * u];
        #pragma unroll
        for (int r = 0; r < 16; ++r) acc[r][u] = bv;
    }

    const float4* __restrict__ Xs4 = reinterpret_cast<const float4*>(Xs);
    #pragma unroll 4
    for (int kc = 0; kc < 32; ++kc) {
        float wv[4][4];
        #pragma unroll
        for (int kk = 0; kk < 4; ++kk)
            #pragma unroll
            for (int u = 0; u < 4; ++u)
                wv[kk][u] = W[(size_t)(4 * kc + kk) * Hn + c + 64 * u];
        #pragma unroll
        for (int r = 0; r < 16; ++r) {
            const float4 xv = Xs4[(mr + r) * 32 + kc];
            #pragma unroll
            for (int u = 0; u < 4; ++u)
                acc[r][u] += xv.x * wv[0][u] + xv.y * wv[1][u] + xv.z * wv[2][u] + xv.w * wv[3][u];
        }
    }

    #pragma unroll
    for (int r = 0; r < 16; ++r)
        #pragma unroll
        for (int u = 0; u < 4; ++u)
            pre[(size_t)(m0 + mr + r) * RS + s * Hn + c + 64 * u] = (_Float16)acc[r][u];
}

// ---------------------------------------------------------------------------
// K3: pre1 (in-place over pre rows) = h0seq(f16) @ [Wih1 | Wax1] + bias
// ---------------------------------------------------------------------------
__global__ void gemm_h_kernel(_Float16* __restrict__ pre,
                              const float* __restrict__ Wih1, const float* __restrict__ bh1,
                              const float* __restrict__ Wax1, const float* __restrict__ ba1)
{
    __shared__ __align__(16) _Float16 Hs[32 * Hn];  // 16 KB
    const int m0 = blockIdx.x * 32;

    {
        float4* __restrict__ dst = reinterpret_cast<float4*>(Hs);
        #pragma unroll
        for (int q = 0; q < 4; ++q) {
            const int id  = threadIdx.x + 256 * q;
            const int row = id >> 5;
            const int off = id & 31;
            const float4* __restrict__ src =
                reinterpret_cast<const float4*>(pre + (size_t)(m0 + row) * RS);
            dst[row * 32 + off] = src[off];
        }
    }
    __syncthreads();

    const int c  = threadIdx.x & 63;
    const int rg = threadIdx.x >> 6;
    const int mr = rg * 8;

    const float* Wp[8];
    float acc[8][8];
    #pragma unroll
    for (int u = 0; u < 8; ++u) {
        const int colu = c + 64 * u;
        const float bv = (colu < Hn) ? bh1[colu] : ba1[colu - Hn];
        Wp[u] = (colu < Hn) ? (Wih1 + colu) : (Wax1 + (colu - Hn));
        #pragma unroll
        for (int r = 0; r < 8; ++r) acc[r][u] = bv;
    }

    const float2* __restrict__ Hs2 = reinterpret_cast<const float2*>(Hs);
    #pragma unroll 2
    for (int kc = 0; kc < 64; ++kc) {
        float wv[4][8];
        #pragma unroll
        for (int kk = 0; kk < 4; ++kk)
            #pragma unroll
            for (int u = 0; u < 8; ++u)
                wv[kk][u] = Wp[u][(size_t)(4 * kc + kk) * Hn];
        #pragma unroll
        for (int r = 0; r < 8; ++r) {
            const float2 q = Hs2[(mr + r) * 64 + kc];
            const h2 p0 = bc2(q.x), p1 = bc2(q.y);
            const float f0 = (float)p0.x, f1 = (float)p0.y, f2 = (float)p1.x, f3 = (float)p1.y;
            #pragma unroll
            for (int u = 0; u < 8; ++u)
                acc[r][u] += f0 * wv[0][u] + f1 * wv[1][u] + f2 * wv[2][u] + f3 * wv[3][u];
        }
    }

    #pragma unroll
    for (int r = 0; r < 8; ++r)
        #pragma unroll
        for (int u = 0; u < 8; ++u)
            pre[(size_t)(m0 + mr + r) * RS + c + 64 * u] = (_Float16)acc[r][u];
}

// ---------------------------------------------------------------------------
// MFMA scan, v2: 64 blocks x 256 threads (4 waves), 1 barrier + 1 LDS
// round-trip per step.
//
// Wave w owns output columns [64w, 64w+64). It computes BOTH matvecs
// (U = tanh-path, A = sigmoid-path) for its columns: 2 matvecs x 4 N-tiles
// x 8 K-chunks = 64 MFMAs/wave/step (same 256/block/step as before, but
// now yU[j] and yA[j] land in the SAME lane -> activation is in-register,
// no y-exchange through LDS, no second barrier).
//
// Lane l of wave w handles column col = 64w + l: selects its y values from
// the 4 N-tile accumulators (3 cndmasks), computes h_new with hprev kept in
// a register, writes 2 bytes to the double-buffered LDS hbuf. One
// __syncthreads per step; double-buffering makes the single barrier
// race-free (write target of step t is the read source of step t+1 only).
//
// Global traffic batched per 8-step chunk in registers (statically indexed
// via full unroll): pre-row prefetch (pUc/pAc), h/out store batch (hst).
// Weights resident in VGPRs: 2 x 4 x 8 f16x8 frags = 256 VGPRs; 
// __launch_bounds__(256,1) gives the 512-VGPR budget (1 wave/SIMD, which is
// all we can use anyway: 64 blocks, lock-stepped waves).
// ---------------------------------------------------------------------------
__global__ __launch_bounds__(256, 1)
void scan_mfma_kernel(_Float16* __restrict__ pre,
                      const float* __restrict__ WU, const float* __restrict__ WA,
                      float* __restrict__ outf, float* __restrict__ hfin, int writeF32)
{
    __shared__ __align__(16) _Float16 hbuf[2][Hn];   // 1 KB

    const int b    = blockIdx.x;
    const int tid  = threadIdx.x;
    const int lane = tid & 63;
    const int w    = tid >> 6;       // wave id: owns cols [64w, 64w+64)
    const int g    = lane >> 4;      // k-subgroup within wave
    const int cl   = lane & 15;      // col within 16-tile
    const int col  = 64 * w + lane;  // this lane's output column

    // ---- B fragments (both weight matrices) resident in VGPRs ----
    f16x8 bU[4][8], bA[4][8];        // [nt][kc]
    #pragma unroll
    for (int nt = 0; nt < 4; ++nt) {
        #pragma unroll
        for (int kc = 0; kc < 8; ++kc) {
            const int n  = 64 * w + 16 * nt + cl;
            const int k0 = 32 * kc + 8 * g;
            f16x8 fu, fa;
            #pragma unroll
            for (int jj = 0; jj < 8; ++jj) {
                fu[jj] = (_Float16)WU[(size_t)(k0 + jj) * Hn + n];
                fa[jj] = (_Float16)WA[(size_t)(k0 + jj) * Hn + n];
            }
            bU[nt][kc] = fu;
            bA[nt][kc] = fa;
        }
    }

    _Float16* __restrict__ rowbase = pre + (size_t)b * Tn * RS;
    float hprev = 0.0f;

    // prologue: h0 = 0; prefetch rows 0..7 into registers
    hbuf[0][tid] = (_Float16)0.0f;
    float pUc[8], pAc[8];
    #pragma unroll
    for (int k = 0; k < 8; ++k) {
        pUc[k] = (float)rowbase[(size_t)k * RS + col];
        pAc[k] = (float)rowbase[(size_t)k * RS + Hn + col];
    }
    __syncthreads();

    for (int t0 = 0; t0 < Tn; t0 += 8) {
        // ---- batched prefetch of rows t0+8 .. t0+15 into registers ----
        float pUn[8], pAn[8];
        #pragma unroll
        for (int k = 0; k < 8; ++k) {
            int tn = t0 + 8 + k;
            if (tn > Tn - 1) tn = Tn - 1;
            pUn[k] = (float)rowbase[(size_t)tn * RS + col];
            pAn[k] = (float)rowbase[(size_t)tn * RS + Hn + col];
        }

        float hst[8];   // h values of this chunk (store batch)

        #pragma unroll
        for (int ph = 0; ph < 8; ++ph) {
            const int t = t0 + ph;

            // ---- A fragments (broadcast h) from current buffer ----
            const float4* __restrict__ hb =
                reinterpret_cast<const float4*>(&hbuf[t & 1][0]);
            f16x8 af[8];
            #pragma unroll
            for (int kc = 0; kc < 8; ++kc)
                af[kc] = __builtin_bit_cast(f16x8, hb[kc * 4 + g]);

            // ---- 8 independent MFMA chains (2 matvecs x 4 N-tiles), 8 deep ----
            const f32x4 z = {0.0f, 0.0f, 0.0f, 0.0f};
            f32x4 aU[4], aA[4];
            #pragma unroll
            for (int nt = 0; nt < 4; ++nt) {
                aU[nt] = __builtin_amdgcn_mfma_f32_16x16x32_f16(af[0], bU[nt][0], z, 0, 0, 0);
                aA[nt] = __builtin_amdgcn_mfma_f32_16x16x32_f16(af[0], bA[nt][0], z, 0, 0, 0);
            }
            #pragma unroll
            for (int kc = 1; kc < 8; ++kc) {
                #pragma unroll
                for (int nt = 0; nt < 4; ++nt) {
                    aU[nt] = __builtin_amdgcn_mfma_f32_16x16x32_f16(af[kc], bU[nt][kc], aU[nt], 0, 0, 0);
                    aA[nt] = __builtin_amdgcn_mfma_f32_16x16x32_f16(af[kc], bA[nt][kc], aA[nt], 0, 0, 0);
                }
            }

            // ---- select this lane's column from the 4 N-tile accumulators
            //      (rows identical -> .x of any row works) ----
            const float u01 = (lane & 16) ? aU[1].x : aU[0].x;
            const float u23 = (lane & 16) ? aU[3].x : aU[2].x;
            const float yU  = (lane & 32) ? u23 : u01;
            const float a01 = (lane & 16) ? aA[1].x : aA[0].x;
            const float a23 = (lane & 16) ? aA[3].x : aA[2].x;
            const float yA  = (lane & 32) ? a23 : a01;

            // ---- in-register activation ----
            const float cand  = fast_tanh(yU + pUc[ph]);
            const float alpha = fast_sigmoid(yA + pAc[ph]);
            const float hn = alpha * cand + (1.0f - alpha) * hprev;
            hprev = hn;
            hst[ph] = hn;
            hbuf[(t + 1) & 1][col] = (_Float16)hn;

            __syncthreads();   // h_new visible; h reads of this step done
        }

        // ---- chunk flush: batched global stores + rotate prefetch regs ----
        if (writeF32) {
            #pragma unroll
            for (int k = 0; k < 8; ++k)
                outf[((size_t)b * Tn + (t0 + k)) * Hn + col] = hst[k];
        } else {
            #pragma unroll
            for (int k = 0; k < 8; ++k)
                rowbase[(size_t)(t0 + k) * RS + col] = (_Float16)hst[k];
        }
        #pragma unroll
        for (int k = 0; k < 8; ++k) { pUc[k] = pUn[k]; pAc[k] = pAn[k]; }
    }

    hfin[b * Hn + col] = hprev;
}

extern "C" void kernel_launch(void* const* d_in, const int* in_sizes, int n_in,
                              void* d_out, int out_size, void* d_ws, size_t ws_size,
                              hipStream_t stream) {
    const float* X    = (const float*)d_in[0];
    const float* Wih0 = (const float*)d_in[1];
    const float* Whh0 = (const float*)d_in[2];
    const float* bh0  = (const float*)d_in[3];
    const float* Wax0 = (const float*)d_in[4];
    const float* Wah0 = (const float*)d_in[5];
    const float* ba0  = (const float*)d_in[6];
    const float* Wih1 = (const float*)d_in[7];
    const float* Whh1 = (const float*)d_in[8];
    const float* bh1  = (const float*)d_in[9];
    const float* Wax1 = (const float*)d_in[10];
    const float* Wah1 = (const float*)d_in[11];
    const float* ba1  = (const float*)d_in[12];

    float* outf = (float*)d_out;
    float* hfin = outf + (size_t)Bn * Tn * Hn;
    _Float16* pre = (_Float16*)d_out;

    gemm_x_kernel<<<dim3((Bn * Tn) / 64, 2), 256, 0, stream>>>(X, Wih0, bh0, Wax0, ba0, pre);
    scan_mfma_kernel<<<dim3(Bn), 256, 0, stream>>>(pre, Whh0, Wah0, outf, hfin, 0);
    gemm_h_kernel<<<dim3((Bn * Tn) / 32), 256, 0, stream>>>(pre, Wih1, bh1, Wax1, ba1);
    scan_mfma_kernel<<<dim3(Bn), 256, 0, stream>>>(pre, Whh1, Wah1, outf, hfin + Bn * Hn, 1);
}

// Round 3
// 4072.304 us; speedup vs baseline: 1.0913x; 1.0483x over previous
//
#include <hip/hip_runtime.h>

#define Bn 64
#define Tn 2048
#define In 128
#define Hn 256
#define RS 512  // row stride in f16 elements for pre/out rows (1024 B)

typedef _Float16 h2 __attribute__((ext_vector_type(2)));
typedef _Float16 f16x8 __attribute__((ext_vector_type(8)));
typedef float f32x4 __attribute__((ext_vector_type(4)));

__device__ __forceinline__ float fast_sigmoid(float x) {
    return 1.0f / (1.0f + __expf(-x));
}
__device__ __forceinline__ float fast_tanh(float x) {
    return 2.0f / (1.0f + __expf(-2.0f * x)) - 1.0f;
}
__device__ __forceinline__ h2 bc2(float f) {
    return __builtin_bit_cast(h2, f);
}

// global -> LDS direct copy, 16 B per lane (wave-uniform LDS base)
__device__ __forceinline__ void gload_lds16(const _Float16* g, _Float16* l) {
    __builtin_amdgcn_global_load_lds(
        (const __attribute__((address_space(1))) void*)g,
        (__attribute__((address_space(3))) void*)l,
        16, 0, 0);
}

// ---------------------------------------------------------------------------
// K1: pre0[m][512] (f16, in d_out) = X[m][0:128] @ [Wih0 | Wax0] + [bh0 | ba0]
// ---------------------------------------------------------------------------
__global__ void gemm_x_kernel(const float* __restrict__ X,
                              const float* __restrict__ Wih0, const float* __restrict__ bh0,
                              const float* __restrict__ Wax0, const float* __restrict__ ba0,
                              _Float16* __restrict__ pre)
{
    __shared__ __align__(16) float Xs[64 * In];  // 32 KB
    const int m0 = blockIdx.x * 64;
    const int s  = blockIdx.y;
    const float* __restrict__ W    = s ? Wax0 : Wih0;
    const float* __restrict__ bias = s ? ba0  : bh0;

    {
        const float4* __restrict__ src = reinterpret_cast<const float4*>(X + (size_t)m0 * In);
        float4* __restrict__ dst = reinterpret_cast<float4*>(Xs);
        #pragma unroll
        for (int i = 0; i < 8; ++i) dst[threadIdx.x + 256 * i] = src[threadIdx.x + 256 * i];
    }
    __syncthreads();

    const int c  = threadIdx.x & 63;
    const int rg = threadIdx.x >> 6;
    const int mr = rg * 16;

    float acc[16][4];
    #pragma unroll
    for (int u = 0; u < 4; ++u) {
        const float bv = bias[c + 64 * u];
        #pragma unroll
        for (int r = 0; r < 16; ++r) acc[r][u] = bv;
    }

    const float4* __restrict__ Xs4 = reinterpret_cast<const float4*>(Xs);
    #pragma unroll 4
    for (int kc = 0; kc < 32; ++kc) {
        float wv[4][4];
        #pragma unroll
        for (int kk = 0; kk < 4; ++kk)
            #pragma unroll
            for (int u = 0; u < 4; ++u)
                wv[kk][u] = W[(size_t)(4 * kc + kk) * Hn + c + 64 * u];
        #pragma unroll
        for (int r = 0; r < 16; ++r) {
            const float4 xv = Xs4[(mr + r) * 32 + kc];
            #pragma unroll
            for (int u = 0; u < 4; ++u)
                acc[r][u] += xv.x * wv[0][u] + xv.y * wv[1][u] + xv.z * wv[2][u] + xv.w * wv[3][u];
        }
    }

    #pragma unroll
    for (int r = 0; r < 16; ++r)
        #pragma unroll
        for (int u = 0; u < 4; ++u)
            pre[(size_t)(m0 + mr + r) * RS + s * Hn + c + 64 * u] = (_Float16)acc[r][u];
}

// ---------------------------------------------------------------------------
// K3: pre1 (in-place over pre rows) = h0seq(f16) @ [Wih1 | Wax1] + bias
// ---------------------------------------------------------------------------
__global__ void gemm_h_kernel(_Float16* __restrict__ pre,
                              const float* __restrict__ Wih1, const float* __restrict__ bh1,
                              const float* __restrict__ Wax1, const float* __restrict__ ba1)
{
    __shared__ __align__(16) _Float16 Hs[32 * Hn];  // 16 KB
    const int m0 = blockIdx.x * 32;

    {
        float4* __restrict__ dst = reinterpret_cast<float4*>(Hs);
        #pragma unroll
        for (int q = 0; q < 4; ++q) {
            const int id  = threadIdx.x + 256 * q;
            const int row = id >> 5;
            const int off = id & 31;
            const float4* __restrict__ src =
                reinterpret_cast<const float4*>(pre + (size_t)(m0 + row) * RS);
            dst[row * 32 + off] = src[off];
        }
    }
    __syncthreads();

    const int c  = threadIdx.x & 63;
    const int rg = threadIdx.x >> 6;
    const int mr = rg * 8;

    const float* Wp[8];
    float acc[8][8];
    #pragma unroll
    for (int u = 0; u < 8; ++u) {
        const int colu = c + 64 * u;
        const float bv = (colu < Hn) ? bh1[colu] : ba1[colu - Hn];
        Wp[u] = (colu < Hn) ? (Wih1 + colu) : (Wax1 + (colu - Hn));
        #pragma unroll
        for (int r = 0; r < 8; ++r) acc[r][u] = bv;
    }

    const float2* __restrict__ Hs2 = reinterpret_cast<const float2*>(Hs);
    #pragma unroll 2
    for (int kc = 0; kc < 64; ++kc) {
        float wv[4][8];
        #pragma unroll
        for (int kk = 0; kk < 4; ++kk)
            #pragma unroll
            for (int u = 0; u < 8; ++u)
                wv[kk][u] = Wp[u][(size_t)(4 * kc + kk) * Hn];
        #pragma unroll
        for (int r = 0; r < 8; ++r) {
            const float2 q = Hs2[(mr + r) * 64 + kc];
            const h2 p0 = bc2(q.x), p1 = bc2(q.y);
            const float f0 = (float)p0.x, f1 = (float)p0.y, f2 = (float)p1.x, f3 = (float)p1.y;
            #pragma unroll
            for (int u = 0; u < 8; ++u)
                acc[r][u] += f0 * wv[0][u] + f1 * wv[1][u] + f2 * wv[2][u] + f3 * wv[3][u];
        }
    }

    #pragma unroll
    for (int r = 0; r < 8; ++r)
        #pragma unroll
        for (int u = 0; u < 8; ++u)
            pre[(size_t)(m0 + mr + r) * RS + c + 64 * u] = (_Float16)acc[r][u];
}

// ---------------------------------------------------------------------------
// MFMA scan, v3: 64 blocks x 1024 threads (16 waves, 4 per SIMD).
//
// Theory: at 1 wave/SIMD a single wave cannot fill the 4-pass XDL pipe; MFMA
// dense-issue cadence degrades to ~16 cy/inst (rocprof: local MfmaUtil ~52%
// for only 64 MFMA/SIMD/step). Fix: 4 independent MFMA-issuing waves per
// SIMD. Wave w = (mv = w>>3, q = (w>>1)&3, kh = w&1): computes matvec mv
// (0=U,1=A) for col-quarter q over K-half kh -> 16 MFMAs/wave/step, still
// 64/SIMD/step, but 4-way wave-interleaved -> pipe fills.
//
// K-half partials combined through yp[2][mv][kh][col] (parity by t&1).
// Step: [af read][16 MFMA][select+publish yp][barrier][act by tid<256,
// hprev in reg, write hbuf + global store][barrier]. Pre-rows prefetched
// per-8-step chunk via global_load_lds into double-buffered pbuf (1 inst
// per wave, waves 0..7), drained by the phase barriers' vmcnt(0).
// Registers/wave: 64 (weights) + 16 (af) + 16 (acc) + temps <= ~128 cap
// at 4 waves/EU.
// ---------------------------------------------------------------------------
__global__ __launch_bounds__(1024, 4)
void scan_mfma_kernel(_Float16* __restrict__ pre,
                      const float* __restrict__ WU, const float* __restrict__ WA,
                      float* __restrict__ outf, float* __restrict__ hfin, int writeF32)
{
    __shared__ __align__(16) _Float16 hbuf[2][Hn];        // 1 KB
    __shared__ __align__(16) float    yp[2][2][2][Hn];    // 8 KB [par][mv][kh][col]
    __shared__ __align__(16) _Float16 pbuf[2][8][2 * Hn]; // 16 KB [chunk par][row][512]

    const int b    = blockIdx.x;
    const int tid  = threadIdx.x;
    const int lane = tid & 63;
    const int w    = tid >> 6;       // wave id 0..15 (uniform)
    const int kh   = w & 1;          // K-half
    const int q    = (w >> 1) & 3;   // 64-col quarter
    const int mv   = w >> 3;         // 0 = U (tanh), 1 = A (sigmoid)
    const int g    = lane >> 4;      // k-subgroup within wave
    const int cl   = lane & 15;      // col within 16-tile

    // ---- B fragments: this wave's [K-half kh] x [col-quarter q] of its matrix ----
    const float* __restrict__ Wm = mv ? WA : WU;
    f16x8 bfrag[4][4];               // [nt][kc]
    #pragma unroll
    for (int nt = 0; nt < 4; ++nt) {
        #pragma unroll
        for (int kc = 0; kc < 4; ++kc) {
            const int n  = 64 * q + 16 * nt + cl;
            const int k0 = 128 * kh + 32 * kc + 8 * g;
            f16x8 f;
            #pragma unroll
            for (int jj = 0; jj < 8; ++jj)
                f[jj] = (_Float16)Wm[(size_t)(k0 + jj) * Hn + n];
            bfrag[nt][kc] = f;
        }
    }

    _Float16* __restrict__ rowbase = pre + (size_t)b * Tn * RS;
    float hprev = 0.0f;

    // prologue: h0 = 0 (tid<256); prefetch rows 0..7 into pbuf[0]
    if (tid < Hn) hbuf[0][tid] = (_Float16)0.0f;
    if (w < 8) gload_lds16(rowbase + (size_t)w * RS + lane * 8, &pbuf[0][w][0]);
    __syncthreads();   // drains vmcnt(0): pbuf[0] ready

    int cb = 0;        // current chunk buffer parity
    for (int t0 = 0; t0 < Tn; t0 += 8) {
        // ---- prefetch next chunk's 8 rows into pbuf[cb^1] (waves 0..7) ----
        if (w < 8) {
            int tn = t0 + 8 + w;
            if (tn > Tn - 1) tn = Tn - 1;
            gload_lds16(rowbase + (size_t)tn * RS + lane * 8, &pbuf[cb ^ 1][w][0]);
        }

        #pragma unroll 1
        for (int ph = 0; ph < 8; ++ph) {
            const int t = t0 + ph;

            // ---- A fragments from hbuf[t&1], K-half kh ----
            const float4* __restrict__ hb =
                reinterpret_cast<const float4*>(&hbuf[t & 1][128 * kh]);
            f16x8 af[4];
            #pragma unroll
            for (int kc = 0; kc < 4; ++kc)
                af[kc] = __builtin_bit_cast(f16x8, hb[kc * 4 + g]);

            // ---- 4 independent MFMA chains (4 N-tiles), 4 deep (K-half) ----
            const f32x4 z = {0.0f, 0.0f, 0.0f, 0.0f};
            f32x4 acc[4];
            #pragma unroll
            for (int nt = 0; nt < 4; ++nt)
                acc[nt] = __builtin_amdgcn_mfma_f32_16x16x32_f16(af[0], bfrag[nt][0], z, 0, 0, 0);
            #pragma unroll
            for (int kc = 1; kc < 4; ++kc) {
                #pragma unroll
                for (int nt = 0; nt < 4; ++nt)
                    acc[nt] = __builtin_amdgcn_mfma_f32_16x16x32_f16(af[kc], bfrag[nt][kc], acc[nt], 0, 0, 0);
            }

            // ---- select this lane's column (rows identical -> .x) & publish ----
            const float y01 = (lane & 16) ? acc[1].x : acc[0].x;
            const float y23 = (lane & 16) ? acc[3].x : acc[2].x;
            const float yv  = (lane & 32) ? y23 : y01;
            yp[t & 1][mv][kh][64 * q + lane] = yv;
            __syncthreads();   // partials ready

            // ---- activation by tid<256; hprev in register ----
            if (tid < Hn) {
                const int j = tid;
                const float yU = yp[t & 1][0][0][j] + yp[t & 1][0][1][j]
                               + (float)pbuf[cb][ph][j];
                const float yA = yp[t & 1][1][0][j] + yp[t & 1][1][1][j]
                               + (float)pbuf[cb][ph][Hn + j];
                const float cand  = fast_tanh(yU);
                const float alpha = fast_sigmoid(yA);
                const float hn = alpha * cand + (1.0f - alpha) * hprev;
                hprev = hn;
                hbuf[(t + 1) & 1][j] = (_Float16)hn;
                if (writeF32) {
                    outf[((size_t)b * Tn + t) * Hn + j] = hn;
                } else {
                    rowbase[(size_t)t * RS + j] = (_Float16)hn;
                }
            }
            __syncthreads();   // hbuf[(t+1)&1] ready for next step
        }
        cb ^= 1;
    }

    if (tid < Hn) hfin[b * Hn + tid] = hprev;
}

extern "C" void kernel_launch(void* const* d_in, const int* in_sizes, int n_in,
                              void* d_out, int out_size, void* d_ws, size_t ws_size,
                              hipStream_t stream) {
    const float* X    = (const float*)d_in[0];
    const float* Wih0 = (const float*)d_in[1];
    const float* Whh0 = (const float*)d_in[2];
    const float* bh0  = (const float*)d_in[3];
    const float* Wax0 = (const float*)d_in[4];
    const float* Wah0 = (const float*)d_in[5];
    const float* ba0  = (const float*)d_in[6];
    const float* Wih1 = (const float*)d_in[7];
    const float* Whh1 = (const float*)d_in[8];
    const float* bh1  = (const float*)d_in[9];
    const float* Wax1 = (const float*)d_in[10];
    const float* Wah1 = (const float*)d_in[11];
    const float* ba1  = (const float*)d_in[12];

    float* outf = (float*)d_out;
    float* hfin = outf + (size_t)Bn * Tn * Hn;
    _Float16* pre = (_Float16*)d_out;

    gemm_x_kernel<<<dim3((Bn * Tn) / 64, 2), 256, 0, stream>>>(X, Wih0, bh0, Wax0, ba0, pre);
    scan_mfma_kernel<<<dim3(Bn), 1024, 0, stream>>>(pre, Whh0, Wah0, outf, hfin, 0);
    gemm_h_kernel<<<dim3((Bn * Tn) / 32), 256, 0, stream>>>(pre, Wih1, bh1, Wax1, ba1);
    scan_mfma_kernel<<<dim3(Bn), 1024, 0, stream>>>(pre, Whh1, Wah1, outf, hfin + Bn * Hn, 1);
}